// Round 1
// baseline (275.293 us; speedup 1.0000x reference)
//
#include <hip/hip_runtime.h>
#include <hip/hip_bf16.h>

#define EPS 1e-3f

typedef __attribute__((ext_vector_type(8))) short short8;
typedef __attribute__((ext_vector_type(4))) float v4f;

__device__ __forceinline__ unsigned short f2bf(float f) {
    unsigned int u = __float_as_uint(f);
    unsigned int r = (u + 0x7fffu + ((u >> 16) & 1u)) >> 16;
    return (unsigned short)r;
}

// ---------------------------------------------------------------------------
// Prep: fold biases + BN into per-channel affine; transpose pw_kernel into
// bf16 MFMA B-fragment layout.  (unchanged from baseline)
// ---------------------------------------------------------------------------
__global__ __launch_bounds__(256) void prep_kernel(
    const float* __restrict__ dwb,
    const float* __restrict__ g1, const float* __restrict__ b1,
    const float* __restrict__ m1, const float* __restrict__ v1,
    const float* __restrict__ pw, const float* __restrict__ pwb,
    const float* __restrict__ g2, const float* __restrict__ b2,
    const float* __restrict__ m2, const float* __restrict__ v2,
    float* __restrict__ scale1, float* __restrict__ shift1,
    float* __restrict__ s2, float* __restrict__ t2,
    unsigned short* __restrict__ Wt)
{
    int tid = threadIdx.x;
    if (blockIdx.x == 0) {
        if (tid < 64) {
            float inv = g1[tid] * rsqrtf(v1[tid] + EPS);
            scale1[tid] = inv;
            shift1[tid] = dwb[tid] * inv + b1[tid] - m1[tid] * inv;
        }
        if (tid < 128) {
            float inv = g2[tid] * rsqrtf(v2[tid] + EPS);
            s2[tid] = inv;
            t2[tid] = pwb[tid] * inv + b2[tid] - m2[tid] * inv;
        }
    }
    int idx = blockIdx.x * 256 + tid;      // 0..8191
    int j     = idx & 7;
    int lane  = (idx >> 3) & 63;
    int kstep = (idx >> 9) & 1;
    int ntile = idx >> 10;                 // 0..7
    int k = kstep * 32 + (lane >> 4) * 8 + j;
    int f = ntile * 16 + (lane & 15);
    Wt[idx] = f2bf(pw[k * 128 + f]);
}

// ---------------------------------------------------------------------------
// Fused: dw 3x3x3 conv + BN1 + ReLU -> bf16 LDS tile -> MFMA pointwise GEMM
// + BN2 + ReLU -> out.
// Block: 256 thr, tile = 4(h) x 16(w) at fixed (b,d) = 64 GEMM rows.
// NEW vs baseline: per-d-slab LDS staging of the 6h x 18w x 64c halo tile
// (zero-filled at h/w edges).  Global x loads drop 54 -> ~21 per thread;
// all edge masks/clamps vanish from the hot loop; xv live set 18 -> 6 f4.
// xS w-stride = 66 floats (264 B, not a multiple of 128 B) so the 4 w-quads
// of a wave land on different bank columns for ds_read_b128.
// ---------------------------------------------------------------------------
__global__ __launch_bounds__(256) void fused_kernel(
    const float* __restrict__ x,
    const float* __restrict__ wgt,          // (3,3,3,1,64)
    const float* __restrict__ scale1,
    const float* __restrict__ shift1,
    const unsigned short* __restrict__ Wt,  // bf16 B-fragments (16 KB)
    const float* __restrict__ s2,
    const float* __restrict__ t2,
    float* __restrict__ out)
{
    __shared__ float wS[27 * 64];
    __shared__ float sS[64];
    __shared__ float tS[64];
    __shared__ float s2S[128];
    __shared__ float t2S[128];
    __shared__ float xS[6 * 18 * 66];       // 28512 B, w-stride 66 floats
    __shared__ unsigned short yS[64 * 72];  // 64 rows x 64 ch, +8 short pad

    int tid = threadIdx.x;
    for (int i = tid; i < 27 * 64; i += 256) wS[i] = wgt[i];
    if (tid < 64) { sS[tid] = scale1[tid]; tS[tid] = shift1[tid]; }
    if (tid < 128) { s2S[tid] = s2[tid]; t2S[tid] = t2[tid]; }
    __syncthreads();

    // XCD-aware decode: xcd = n&7 owns bd in [xcd*12, xcd*12+12)
    int n   = blockIdx.x;
    int xcd = n & 7;
    int j   = n >> 3;              // 0..431
    int bd  = xcd * 12 + (j % 12); // 0..95
    int s   = j / 12;              // 0..35
    int w0  = (s % 3) * 16;
    int h0  = (s / 3) * 4;
    int b   = bd / 48;
    int d   = bd % 48;

    int tx = tid & 15;            // channel group
    int ty = tid >> 4;            // 0..15
    int c0 = tx * 4;
    int wq = ty & 3;
    int rh = ty >> 2;             // == wave id -> h is wave-uniform

    float4 acc[4];
    #pragma unroll
    for (int r = 0; r < 4; ++r) acc[r] = make_float4(0.f, 0.f, 0.f, 0.f);

    #pragma unroll
    for (int dd = 0; dd < 3; ++dd) {
        int zd = d + dd - 1;
        if (zd >= 0 && zd < 48) {              // block-uniform
            // ---- stage slab (6h x 18w x 16 c-groups = 1728 float4) ----
            const float* xs = x + (long)(b * 48 + zd) * (48 * 48 * 64);
            #pragma unroll
            for (int i = 0; i < 7; ++i) {
                int idx = i * 256 + tid;
                if (idx < 1728) {
                    int cg = idx & 15;
                    int hw = idx >> 4;         // 0..107
                    int hh = hw / 18;
                    int ww = hw - hh * 18;
                    int zh = h0 + hh - 1;
                    int zw = w0 + ww - 1;
                    float4 v = make_float4(0.f, 0.f, 0.f, 0.f);
                    if (zh >= 0 && zh < 48 && zw >= 0 && zw < 48)
                        v = *(const float4*)(xs + (zh * 48 + zw) * 64 + cg * 4);
                    *(float4*)(&xS[(hh * 18 + ww) * 66 + cg * 4]) = v;
                }
            }
            __syncthreads();

            // ---- conv from LDS: no masks, no clamps ----
            #pragma unroll
            for (int hh = 0; hh < 3; ++hh) {
                const float* rp = &xS[((rh + hh) * 18 + wq * 4) * 66 + c0];
                float4 xv[6];
                #pragma unroll
                for (int p = 0; p < 6; ++p)
                    xv[p] = *(const float4*)(rp + p * 66);
                #pragma unroll
                for (int ww = 0; ww < 3; ++ww) {
                    const float4 wv = *(const float4*)(&wS[((dd * 3 + hh) * 3 + ww) * 64 + c0]);
                    #pragma unroll
                    for (int r = 0; r < 4; ++r) {
                        acc[r].x += xv[r + ww].x * wv.x;
                        acc[r].y += xv[r + ww].y * wv.y;
                        acc[r].z += xv[r + ww].z * wv.z;
                        acc[r].w += xv[r + ww].w * wv.w;
                    }
                }
            }
            __syncthreads();                   // slab reusable next dd
        }
    }

    // BN1 + ReLU + bf16 -> LDS (row = ty*4+r, padded stride 72 shorts)
    {
        float4 s1 = *(const float4*)(&sS[c0]);
        float4 t1 = *(const float4*)(&tS[c0]);
        #pragma unroll
        for (int r = 0; r < 4; ++r) {
            ushort4 o;
            o.x = f2bf(fmaxf(acc[r].x * s1.x + t1.x, 0.f));
            o.y = f2bf(fmaxf(acc[r].y * s1.y + t1.y, 0.f));
            o.z = f2bf(fmaxf(acc[r].z * s1.z + t1.z, 0.f));
            o.w = f2bf(fmaxf(acc[r].w * s1.w + t1.w, 0.f));
            *(ushort4*)(&yS[(ty * 4 + r) * 72 + c0]) = o;
        }
    }
    __syncthreads();

    // GEMM: 4 waves, wave = 16 rows x 128 cols, K=64 in 2 MFMA k-steps
    int wv   = tid >> 6;
    int lane = tid & 63;
    int lrow = lane & 15;
    int quad = lane >> 4;

    const short8 a0 = *(const short8*)(&yS[(wv * 16 + lrow) * 72 + quad * 8]);
    const short8 a1 = *(const short8*)(&yS[(wv * 16 + lrow) * 72 + 32 + quad * 8]);

    v4f g[8];
    #pragma unroll
    for (int nn = 0; nn < 8; ++nn) g[nn] = (v4f){0.f, 0.f, 0.f, 0.f};

    #pragma unroll
    for (int nn = 0; nn < 8; ++nn) {
        short8 b0 = *(const short8*)(Wt + ((nn * 2 + 0) * 64 + lane) * 8);
        short8 b1 = *(const short8*)(Wt + ((nn * 2 + 1) * 64 + lane) * 8);
        g[nn] = __builtin_amdgcn_mfma_f32_16x16x32_bf16(a0, b0, g[nn], 0, 0, 0);
        g[nn] = __builtin_amdgcn_mfma_f32_16x16x32_bf16(a1, b1, g[nn], 0, 0, 0);
    }

    // BN2 + ReLU epilogue. D: col=lane&15, row=quad*4+reg.
    long base_out = ((((long)b * 48 + d) * 48 + (h0 + wv)) * 48 + w0) * 128;
    #pragma unroll
    for (int nn = 0; nn < 8; ++nn) {
        int f = nn * 16 + lrow;
        float sf = s2S[f];
        float tf = t2S[f];
        #pragma unroll
        for (int r = 0; r < 4; ++r) {
            float v = fmaxf(g[nn][r] * sf + tf, 0.f);
            out[base_out + (quad * 4 + r) * 128 + f] = v;
        }
    }
}

// ---------------------------------------------------------------------------
extern "C" void kernel_launch(void* const* d_in, const int* in_sizes, int n_in,
                              void* d_out, int out_size, void* d_ws, size_t ws_size,
                              hipStream_t stream)
{
    const float* x   = (const float*)d_in[0];
    const float* dwk = (const float*)d_in[1];
    const float* dwb = (const float*)d_in[2];
    const float* g1  = (const float*)d_in[3];
    const float* b1  = (const float*)d_in[4];
    const float* m1  = (const float*)d_in[5];
    const float* v1  = (const float*)d_in[6];
    const float* pw  = (const float*)d_in[7];
    const float* pwb = (const float*)d_in[8];
    const float* g2  = (const float*)d_in[9];
    const float* b2  = (const float*)d_in[10];
    const float* m2  = (const float*)d_in[11];
    const float* v2  = (const float*)d_in[12];

    float* outp = (float*)d_out;

    float* scale1 = (float*)d_ws;
    float* shift1 = scale1 + 64;
    float* s2     = scale1 + 128;
    float* t2     = scale1 + 256;
    unsigned short* Wt = (unsigned short*)((char*)d_ws + 2048);

    hipLaunchKernelGGL(prep_kernel, dim3(32), dim3(256), 0, stream,
                       dwb, g1, b1, m1, v1, pw, pwb, g2, b2, m2, v2,
                       scale1, shift1, s2, t2, Wt);

    hipLaunchKernelGGL(fused_kernel, dim3(3456), dim3(256), 0, stream,
                       x, dwk, scale1, shift1, Wt, s2, t2, outp);
}

// Round 2
// 235.809 us; speedup vs baseline: 1.1674x; 1.1674x over previous
//
#include <hip/hip_runtime.h>
#include <hip/hip_bf16.h>

#define EPS 1e-3f

typedef __attribute__((ext_vector_type(8))) short short8;
typedef __attribute__((ext_vector_type(4))) float v4f;

__device__ __forceinline__ unsigned short f2bf(float f) {
    unsigned int u = __float_as_uint(f);
    unsigned int r = (u + 0x7fffu + ((u >> 16) & 1u)) >> 16;
    return (unsigned short)r;
}

// ---------------------------------------------------------------------------
// Prep: fold biases + BN into per-channel affine; transpose pw_kernel into
// bf16 MFMA B-fragment layout.  (unchanged)
// ---------------------------------------------------------------------------
__global__ __launch_bounds__(256) void prep_kernel(
    const float* __restrict__ dwb,
    const float* __restrict__ g1, const float* __restrict__ b1,
    const float* __restrict__ m1, const float* __restrict__ v1,
    const float* __restrict__ pw, const float* __restrict__ pwb,
    const float* __restrict__ g2, const float* __restrict__ b2,
    const float* __restrict__ m2, const float* __restrict__ v2,
    float* __restrict__ scale1, float* __restrict__ shift1,
    float* __restrict__ s2, float* __restrict__ t2,
    unsigned short* __restrict__ Wt)
{
    int tid = threadIdx.x;
    if (blockIdx.x == 0) {
        if (tid < 64) {
            float inv = g1[tid] * rsqrtf(v1[tid] + EPS);
            scale1[tid] = inv;
            shift1[tid] = dwb[tid] * inv + b1[tid] - m1[tid] * inv;
        }
        if (tid < 128) {
            float inv = g2[tid] * rsqrtf(v2[tid] + EPS);
            s2[tid] = inv;
            t2[tid] = pwb[tid] * inv + b2[tid] - m2[tid] * inv;
        }
    }
    int idx = blockIdx.x * 256 + tid;      // 0..8191
    int j     = idx & 7;
    int lane  = (idx >> 3) & 63;
    int kstep = (idx >> 9) & 1;
    int ntile = idx >> 10;                 // 0..7
    int k = kstep * 32 + (lane >> 4) * 8 + j;
    int f = ntile * 16 + (lane & 15);
    Wt[idx] = f2bf(pw[k * 128 + f]);
}

// ---------------------------------------------------------------------------
// Fused, multi-d sliding-window version.
// Block: 256 thr, hw-tile = 4(h) x 16(w), DPB=4 consecutive output-d slices.
// Streams 6 slabs (d0-1 .. d0+4) through one LDS buffer; each slab feeds up
// to 3 rotating conv accumulators (shared ds_reads, distinct weight taps).
// Finish (BN1 -> yS -> MFMA GEMM -> BN2 -> store) for output d0+k-2 overlaps
// with staging/conv of later slabs. 13 syncs / 4 outputs (was ~8 / 1).
// ---------------------------------------------------------------------------
__global__ __launch_bounds__(256, 3) void fused_kernel(
    const float* __restrict__ x,
    const float* __restrict__ wgt,          // (3,3,3,1,64)
    const float* __restrict__ scale1,
    const float* __restrict__ shift1,
    const unsigned short* __restrict__ Wt,  // bf16 B-fragments (16 KB)
    const float* __restrict__ s2,
    const float* __restrict__ t2,
    float* __restrict__ out)
{
    __shared__ float wS[27 * 64];
    __shared__ float sS[64];
    __shared__ float tS[64];
    __shared__ float s2S[128];
    __shared__ float t2S[128];
    __shared__ float xS[6 * 18 * 66];       // 28512 B, w-stride 66 floats
    __shared__ unsigned short yS[64 * 72];  // 64 rows x 64 ch, +8 short pad

    int tid = threadIdx.x;
    for (int i = tid; i < 27 * 64; i += 256) wS[i] = wgt[i];
    if (tid < 64) { sS[tid] = scale1[tid]; tS[tid] = shift1[tid]; }
    if (tid < 128) { s2S[tid] = s2[tid]; t2S[tid] = t2[tid]; }
    __syncthreads();

    // XCD-aware decode: 864 blocks = 8 xcd * 3 (b,dgrp) * 36 hw
    int n   = blockIdx.x;
    int xcd = n & 7;
    int j   = n >> 3;              // 0..107
    int bdg = xcd * 3 + j / 36;    // 0..23  (b*12 + dgrp)
    int hw  = j % 36;
    int b    = bdg / 12;
    int dgrp = bdg % 12;
    int d0   = dgrp * 4;
    int w0  = (hw % 3) * 16;
    int h0  = (hw / 3) * 4;

    int tx = tid & 15;            // channel group
    int ty = tid >> 4;            // 0..15
    int c0 = tx * 4;
    int wq = ty & 3;
    int rh = ty >> 2;             // == wave id -> h is wave-uniform

    int wv   = tid >> 6;
    int lane = tid & 63;
    int lrow = lane & 15;
    int quad = lane >> 4;

    // 3 rotating accumulator sets (all indices compile-time after unroll)
    float4 acc[3][4];
    #pragma unroll
    for (int a = 0; a < 3; ++a)
        #pragma unroll
        for (int r = 0; r < 4; ++r) acc[a][r] = make_float4(0.f, 0.f, 0.f, 0.f);

    #pragma unroll
    for (int k = 0; k < 6; ++k) {
        int s = d0 - 1 + k;                    // slab depth
        bool s_ok = (s >= 0) && (s < 48);      // block-uniform

        // ---- stage slab (6h x 18w x 16 c-groups = 1728 float4) ----
        if (s_ok) {
            const float* xs = x + (long)(b * 48 + s) * (48 * 48 * 64);
            #pragma unroll
            for (int i = 0; i < 7; ++i) {
                int idx = i * 256 + tid;
                if (idx < 1728) {
                    int cg = idx & 15;
                    int hwl = idx >> 4;        // 0..107
                    int hh = hwl / 18;
                    int ww = hwl - hh * 18;
                    int zh = h0 + hh - 1;
                    int zw = w0 + ww - 1;
                    float4 v = make_float4(0.f, 0.f, 0.f, 0.f);
                    if (zh >= 0 && zh < 48 && zw >= 0 && zw < 48)
                        v = *(const float4*)(xs + (zh * 48 + zw) * 64 + cg * 4);
                    *(float4*)(&xS[(hh * 18 + ww) * 66 + cg * 4]) = v;
                }
            }
        }
        __syncthreads();

        // ---- conv: 18 shared ds_reads feed up to 3 output accumulators ----
        if (s_ok) {
            #pragma unroll
            for (int hh = 0; hh < 3; ++hh) {
                const float* rp = &xS[((rh + hh) * 18 + wq * 4) * 66 + c0];
                float4 xv[6];
                #pragma unroll
                for (int p = 0; p < 6; ++p)
                    xv[p] = *(const float4*)(rp + p * 66);
                #pragma unroll
                for (int m = 0; m < 4; ++m) {
                    if (m >= k - 2 && m <= k) {      // folds at compile time
                        const int wz  = k - m;       // weight z-tap
                        const int aid = m % 3;
                        #pragma unroll
                        for (int ww = 0; ww < 3; ++ww) {
                            const float4 wvv = *(const float4*)(&wS[((wz * 3 + hh) * 3 + ww) * 64 + c0]);
                            #pragma unroll
                            for (int r = 0; r < 4; ++r) {
                                acc[aid][r].x += xv[r + ww].x * wvv.x;
                                acc[aid][r].y += xv[r + ww].y * wvv.y;
                                acc[aid][r].z += xv[r + ww].z * wvv.z;
                                acc[aid][r].w += xv[r + ww].w * wvv.w;
                            }
                        }
                    }
                }
            }
        }

        // ---- finish output m = k-2 (always valid for k>=2) ----
        if (k >= 2) {
            const int m   = k - 2;
            const int aid = m % 3;
            // BN1 + ReLU + bf16 -> yS
            {
                float4 s1 = *(const float4*)(&sS[c0]);
                float4 t1 = *(const float4*)(&tS[c0]);
                #pragma unroll
                for (int r = 0; r < 4; ++r) {
                    ushort4 o;
                    o.x = f2bf(fmaxf(acc[aid][r].x * s1.x + t1.x, 0.f));
                    o.y = f2bf(fmaxf(acc[aid][r].y * s1.y + t1.y, 0.f));
                    o.z = f2bf(fmaxf(acc[aid][r].z * s1.z + t1.z, 0.f));
                    o.w = f2bf(fmaxf(acc[aid][r].w * s1.w + t1.w, 0.f));
                    *(ushort4*)(&yS[(ty * 4 + r) * 72 + c0]) = o;
                    acc[aid][r] = make_float4(0.f, 0.f, 0.f, 0.f);  // recycle
                }
            }
            __syncthreads();

            // GEMM: 4 waves, wave = 16 rows x 128 cols, K=64, 2 MFMA k-steps
            const short8 a0 = *(const short8*)(&yS[(wv * 16 + lrow) * 72 + quad * 8]);
            const short8 a1 = *(const short8*)(&yS[(wv * 16 + lrow) * 72 + 32 + quad * 8]);

            v4f g[8];
            #pragma unroll
            for (int nn = 0; nn < 8; ++nn) g[nn] = (v4f){0.f, 0.f, 0.f, 0.f};

            #pragma unroll
            for (int nn = 0; nn < 8; ++nn) {
                short8 b0 = *(const short8*)(Wt + ((nn * 2 + 0) * 64 + lane) * 8);
                short8 b1 = *(const short8*)(Wt + ((nn * 2 + 1) * 64 + lane) * 8);
                g[nn] = __builtin_amdgcn_mfma_f32_16x16x32_bf16(a0, b0, g[nn], 0, 0, 0);
                g[nn] = __builtin_amdgcn_mfma_f32_16x16x32_bf16(a1, b1, g[nn], 0, 0, 0);
            }

            // BN2 + ReLU epilogue. D: col=lane&15, row=quad*4+reg.
            int d = d0 + m;
            long base_out = ((((long)b * 48 + d) * 48 + (h0 + wv)) * 48 + w0) * 128;
            #pragma unroll
            for (int nn = 0; nn < 8; ++nn) {
                int f = nn * 16 + lrow;
                float sf = s2S[f];
                float tf = t2S[f];
                #pragma unroll
                for (int r = 0; r < 4; ++r) {
                    float v = fmaxf(g[nn][r] * sf + tf, 0.f);
                    out[base_out + (quad * 4 + r) * 128 + f] = v;
                }
            }
        } else {
            __syncthreads();   // protect xS before next stage
        }
    }
}

// ---------------------------------------------------------------------------
extern "C" void kernel_launch(void* const* d_in, const int* in_sizes, int n_in,
                              void* d_out, int out_size, void* d_ws, size_t ws_size,
                              hipStream_t stream)
{
    const float* x   = (const float*)d_in[0];
    const float* dwk = (const float*)d_in[1];
    const float* dwb = (const float*)d_in[2];
    const float* g1  = (const float*)d_in[3];
    const float* b1  = (const float*)d_in[4];
    const float* m1  = (const float*)d_in[5];
    const float* v1  = (const float*)d_in[6];
    const float* pw  = (const float*)d_in[7];
    const float* pwb = (const float*)d_in[8];
    const float* g2  = (const float*)d_in[9];
    const float* b2  = (const float*)d_in[10];
    const float* m2  = (const float*)d_in[11];
    const float* v2  = (const float*)d_in[12];

    float* outp = (float*)d_out;

    float* scale1 = (float*)d_ws;
    float* shift1 = scale1 + 64;
    float* s2     = scale1 + 128;
    float* t2     = scale1 + 256;
    unsigned short* Wt = (unsigned short*)((char*)d_ws + 2048);

    hipLaunchKernelGGL(prep_kernel, dim3(32), dim3(256), 0, stream,
                       dwb, g1, b1, m1, v1, pw, pwb, g2, b2, m2, v2,
                       scale1, shift1, s2, t2, Wt);

    hipLaunchKernelGGL(fused_kernel, dim3(864), dim3(256), 0, stream,
                       x, dwk, scale1, shift1, Wt, s2, t2, outp);
}